// Round 4
// baseline (42.999 us; speedup 1.0000x reference)
//
#include <hip/hip_runtime.h>

#define NPART   2048
#define NCOMP   8192
#define NBATCH  8
#define THRESH  0.05f
#define FLTMAX  3.4028235e38f

#define SLOTS   64                        // point-slots per block
#define SEGS    16                        // one segment per wave
#define SEGLEN  (NPART / SEGS)            // 128 partials per wave
#define PPT     2                         // completed points per thread
#define PTSBLK  (SLOTS * PPT)             // 128 completed points per block
#define BLKSPB  (NCOMP / PTSBLK)          // 64 blocks per batch
#define GRID    (NBATCH * BLKSPB)         // 512 blocks -> 8192 waves = full device

// ws layout: [0]=sum(f32) [1]=cnt(u32) [2]=ticket(u32), table at +256 bytes
#define TBL_OFF 256

__global__ __launch_bounds__(256) void pml_prep(
    const float* __restrict__ partial,
    float4* __restrict__ table,
    unsigned int* __restrict__ hdr)
{
    int i = blockIdx.x * 256 + threadIdx.x;          // 0 .. 16383
    if (i == 0) { hdr[0] = 0u; hdr[1] = 0u; hdr[2] = 0u; }
    float x = partial[3 * i + 0];
    float y = partial[3 * i + 1];
    float z = partial[3 * i + 2];
    table[i] = make_float4(x, y, z, fmaf(x, x, fmaf(y, y, z * z)));
}

__global__ __launch_bounds__(1024, 8) void pml_main(
    const float* __restrict__ completed,
    const float4* __restrict__ table,
    float* __restrict__ ws_sum,
    unsigned int* __restrict__ ws_cnt,
    unsigned int* __restrict__ ws_ticket,
    float* __restrict__ out)
{
    const int tid  = threadIdx.x;
    const int slot = tid & (SLOTS - 1);
    // readfirstlane -> SGPR: provably wave-uniform so the partial-table
    // address is uniform and the loads become s_load (scalar cache, no LDS).
    const int seg  = __builtin_amdgcn_readfirstlane(tid >> 6);
    const int batch = blockIdx.x >> 6;
    const int blkb  = blockIdx.x & (BLKSPB - 1);

    __shared__ float smin[PTSBLK][SEGS + 1];   // pad 17 -> 2-way banks (free)
    __shared__ float sc2[PTSBLK];
    __shared__ float        rs[2];
    __shared__ unsigned int rc[2];

    // ---- this thread's completed points ----
    const float* cb = completed + ((size_t)batch * NCOMP + (size_t)blkb * PTSBLK) * 3;
    float nx[PPT], ny[PPT], nz[PPT], c2[PPT];
    #pragma unroll
    for (int k = 0; k < PPT; ++k) {
        int p = slot + k * SLOTS;
        float x = cb[3 * p + 0];
        float y = cb[3 * p + 1];
        float z = cb[3 * p + 2];
        nx[k] = -2.0f * x;
        ny[k] = -2.0f * y;
        nz[k] = -2.0f * z;
        c2[k] = fmaf(x, x, fmaf(y, y, z * z));
    }

    // ---- scan this wave's 128-partial segment (scalar loads, SGPR data) ----
    const float4* s = table + (size_t)batch * NPART + (size_t)seg * SEGLEN;
    float acc[PPT][4];
    #pragma unroll
    for (int k = 0; k < PPT; ++k)
        #pragma unroll
        for (int u = 0; u < 4; ++u) acc[k][u] = FLTMAX;

    for (int j = 0; j < SEGLEN; j += 4) {
        float4 p0 = s[j + 0];
        float4 p1 = s[j + 1];
        float4 p2 = s[j + 2];
        float4 p3 = s[j + 3];
        #pragma unroll
        for (int k = 0; k < PPT; ++k) {
            acc[k][0] = fminf(acc[k][0], fmaf(p0.x, nx[k], fmaf(p0.y, ny[k], fmaf(p0.z, nz[k], p0.w))));
            acc[k][1] = fminf(acc[k][1], fmaf(p1.x, nx[k], fmaf(p1.y, ny[k], fmaf(p1.z, nz[k], p1.w))));
            acc[k][2] = fminf(acc[k][2], fmaf(p2.x, nx[k], fmaf(p2.y, ny[k], fmaf(p2.z, nz[k], p2.w))));
            acc[k][3] = fminf(acc[k][3], fmaf(p3.x, nx[k], fmaf(p3.y, ny[k], fmaf(p3.z, nz[k], p3.w))));
        }
    }

    #pragma unroll
    for (int k = 0; k < PPT; ++k) {
        int p = slot + k * SLOTS;
        smin[p][seg] = fminf(fminf(acc[k][0], acc[k][1]), fminf(acc[k][2], acc[k][3]));
        if (seg == 0) sc2[p] = c2[k];
    }
    __syncthreads();

    // ---- combine segments, mask, block-reduce ----
    float        v = 0.0f;
    unsigned int c = 0u;
    if (tid < PTSBLK) {
        float t = smin[tid][0];
        #pragma unroll
        for (int g = 1; g < SEGS; ++g) t = fminf(t, smin[tid][g]);
        float m = fmaxf(sc2[tid] + t, 0.0f);
        if (m < THRESH) { v = m; c = 1u; }
        #pragma unroll
        for (int off = 32; off >= 1; off >>= 1) {
            v += __shfl_down(v, off, 64);
            c += __shfl_down(c, off, 64);
        }
        if ((tid & 63) == 0) { rs[tid >> 6] = v; rc[tid >> 6] = c; }
    }
    __syncthreads();

    // ---- accumulate + last-block finalize (saves the fin launch) ----
    if (tid == 0) {
        atomicAdd(ws_sum, rs[0] + rs[1]);
        atomicAdd(ws_cnt, rc[0] + rc[1]);
        __threadfence();
        unsigned int t = __hip_atomic_fetch_add(ws_ticket, 1u, __ATOMIC_ACQ_REL,
                                                __HIP_MEMORY_SCOPE_AGENT);
        if (t == GRID - 1) {
            float        s2 = __hip_atomic_load(ws_sum, __ATOMIC_ACQUIRE,
                                                __HIP_MEMORY_SCOPE_AGENT);
            unsigned int cc = __hip_atomic_load(ws_cnt, __ATOMIC_ACQUIRE,
                                                __HIP_MEMORY_SCOPE_AGENT);
            *out = (cc > 0u) ? (s2 / ((float)cc + 1e-6f)) : 0.0f;   // WEIGHT = 1.0
        }
    }
}

extern "C" void kernel_launch(void* const* d_in, const int* in_sizes, int n_in,
                              void* d_out, int out_size, void* d_ws, size_t ws_size,
                              hipStream_t stream) {
    const float* completed = (const float*)d_in[0];  // (8, 8192, 3) f32
    const float* partial   = (const float*)d_in[1];  // (8, 2048, 3) f32
    float* out = (float*)d_out;

    float*        ws_sum    = (float*)d_ws;
    unsigned int* ws_cnt    = (unsigned int*)d_ws + 1;
    unsigned int* ws_ticket = (unsigned int*)d_ws + 2;
    float4*       table     = (float4*)((char*)d_ws + TBL_OFF);

    // prep zeros the accumulators itself (ws is poisoned once, never re-poisoned)
    pml_prep<<<dim3((NBATCH * NPART) / 256), dim3(256), 0, stream>>>(
        partial, table, (unsigned int*)d_ws);
    pml_main<<<dim3(GRID), dim3(1024), 0, stream>>>(
        completed, table, ws_sum, ws_cnt, ws_ticket, out);
}

// Round 5
// 36.016 us; speedup vs baseline: 1.1939x; 1.1939x over previous
//
#include <hip/hip_runtime.h>

#define NPART   2048
#define NCOMP   8192
#define NBATCH  8
#define THRESH  0.05f
#define FLTMAX  3.4028235e38f

#define SLOTS   32                        // point-slots per block
#define SEGS    32                        // partial segments (tid>>5)
#define SEGLEN  (NPART / SEGS)            // 64 partials per segment
#define PPT     8                         // completed points per thread
#define PTSBLK  (SLOTS * PPT)             // 256 completed points per block
#define BLKSPB  (NCOMP / PTSBLK)          // 32 blocks per batch
#define GRID    (NBATCH * BLKSPB)         // 256 blocks, 16 waves each

__global__ __launch_bounds__(1024, 4) void pml_main(
    const float* __restrict__ completed,
    const float* __restrict__ partial,
    float* __restrict__ ws_sum,
    unsigned int* __restrict__ ws_cnt,
    unsigned int* __restrict__ ws_ticket,
    float* __restrict__ out)
{
    const int tid   = threadIdx.x;
    const int slot  = tid & (SLOTS - 1);
    const int seg   = tid >> 5;              // 0..31; half-wave uniform -> the
                                             // paired ds_read_b128 is a 2-way
                                             // alias = free (m136)
    const int batch = blockIdx.x >> 5;
    const int blkb  = blockIdx.x & (BLKSPB - 1);

    __shared__ float4 sp[NPART];             // 32 KB: (x,y,z,|p|^2)
    __shared__ float  smin[PTSBLK][SEGS + 1];// 33 KB, pad 33 -> conflict-free
    __shared__ float  sc2[PTSBLK];
    __shared__ float        rs[4];
    __shared__ unsigned int rc[4];

    // ---- stage partials into LDS, precompute |p|^2 ----
    {
        const float* pb = partial + (size_t)batch * NPART * 3;
        #pragma unroll
        for (int k = 0; k < 2; ++k) {
            int j = k * 1024 + tid;
            float x = pb[3 * j + 0];
            float y = pb[3 * j + 1];
            float z = pb[3 * j + 2];
            sp[j] = make_float4(x, y, z, fmaf(x, x, fmaf(y, y, z * z)));
        }
    }

    // ---- this thread's 8 completed points (stride-32 -> coalesced) ----
    const float* cb = completed + ((size_t)batch * NCOMP + (size_t)blkb * PTSBLK) * 3;
    float nx[PPT], ny[PPT], nz[PPT], c2[PPT];
    #pragma unroll
    for (int k = 0; k < PPT; ++k) {
        int p = slot + k * SLOTS;
        float x = cb[3 * p + 0];
        float y = cb[3 * p + 1];
        float z = cb[3 * p + 2];
        nx[k] = -2.0f * x;
        ny[k] = -2.0f * y;
        nz[k] = -2.0f * z;
        c2[k] = fmaf(x, x, fmaf(y, y, z * z));
    }

    __syncthreads();

    // ---- scan this segment's 64 partials for 8 points ----
    // t = |p|^2 - 2 c.p ; 32 independent min chains (8 pts x 4 unroll).
    // Per 4-partial step: 4 ds_read_b128 (48 CU-cyc) vs 128 VALU (64 CU-cyc)
    // -> VALU-bound (round 3 at PPT=4 was 1.5x LDS-bound).
    const float4* s = sp + seg * SEGLEN;
    float acc[PPT][4];
    #pragma unroll
    for (int k = 0; k < PPT; ++k)
        #pragma unroll
        for (int u = 0; u < 4; ++u) acc[k][u] = FLTMAX;

    for (int j = 0; j < SEGLEN; j += 4) {
        float4 p0 = s[j + 0];
        float4 p1 = s[j + 1];
        float4 p2 = s[j + 2];
        float4 p3 = s[j + 3];
        #pragma unroll
        for (int k = 0; k < PPT; ++k) {
            acc[k][0] = fminf(acc[k][0], fmaf(p0.x, nx[k], fmaf(p0.y, ny[k], fmaf(p0.z, nz[k], p0.w))));
            acc[k][1] = fminf(acc[k][1], fmaf(p1.x, nx[k], fmaf(p1.y, ny[k], fmaf(p1.z, nz[k], p1.w))));
            acc[k][2] = fminf(acc[k][2], fmaf(p2.x, nx[k], fmaf(p2.y, ny[k], fmaf(p2.z, nz[k], p2.w))));
            acc[k][3] = fminf(acc[k][3], fmaf(p3.x, nx[k], fmaf(p3.y, ny[k], fmaf(p3.z, nz[k], p3.w))));
        }
    }

    #pragma unroll
    for (int k = 0; k < PPT; ++k) {
        int p = slot + k * SLOTS;
        // bank(p*33 + seg) = (slot + seg) % 32 within each half-wave: conflict-free
        smin[p][seg] = fminf(fminf(acc[k][0], acc[k][1]), fminf(acc[k][2], acc[k][3]));
        if (seg == 0) sc2[p] = c2[k];
    }
    __syncthreads();

    // ---- combine 32 segments per point, mask, block-reduce ----
    float        v = 0.0f;
    unsigned int c = 0u;
    if (tid < PTSBLK) {
        float t = smin[tid][0];
        #pragma unroll
        for (int g = 1; g < SEGS; ++g) t = fminf(t, smin[tid][g]);
        float m = fmaxf(sc2[tid] + t, 0.0f);
        if (m < THRESH) { v = m; c = 1u; }
        #pragma unroll
        for (int off = 32; off >= 1; off >>= 1) {
            v += __shfl_down(v, off, 64);
            c += __shfl_down(c, off, 64);
        }
        if ((tid & 63) == 0) { rs[tid >> 6] = v; rc[tid >> 6] = c; }
    }
    __syncthreads();

    // ---- accumulate + last-block finalize (no separate fin kernel) ----
    if (tid == 0) {
        atomicAdd(ws_sum, rs[0] + rs[1] + rs[2] + rs[3]);
        atomicAdd(ws_cnt, rc[0] + rc[1] + rc[2] + rc[3]);
        __threadfence();
        unsigned int t = __hip_atomic_fetch_add(ws_ticket, 1u, __ATOMIC_ACQ_REL,
                                                __HIP_MEMORY_SCOPE_AGENT);
        if (t == GRID - 1) {
            float        s2 = __hip_atomic_load(ws_sum, __ATOMIC_ACQUIRE,
                                                __HIP_MEMORY_SCOPE_AGENT);
            unsigned int cc = __hip_atomic_load(ws_cnt, __ATOMIC_ACQUIRE,
                                                __HIP_MEMORY_SCOPE_AGENT);
            *out = (cc > 0u) ? (s2 / ((float)cc + 1e-6f)) : 0.0f;   // WEIGHT = 1.0
        }
    }
}

extern "C" void kernel_launch(void* const* d_in, const int* in_sizes, int n_in,
                              void* d_out, int out_size, void* d_ws, size_t ws_size,
                              hipStream_t stream) {
    const float* completed = (const float*)d_in[0];  // (8, 8192, 3) f32
    const float* partial   = (const float*)d_in[1];  // (8, 2048, 3) f32
    float* out = (float*)d_out;

    float*        ws_sum    = (float*)d_ws;
    unsigned int* ws_cnt    = (unsigned int*)d_ws + 1;
    unsigned int* ws_ticket = (unsigned int*)d_ws + 2;

    // ws is poisoned once and never re-poisoned between replays: zero the
    // three accumulator words every call (memset node is capture-safe).
    hipMemsetAsync(d_ws, 0, 12, stream);

    pml_main<<<dim3(GRID), dim3(1024), 0, stream>>>(
        completed, partial, ws_sum, ws_cnt, ws_ticket, out);
}

// Round 6
// 23.146 us; speedup vs baseline: 1.8577x; 1.5560x over previous
//
#include <hip/hip_runtime.h>

#define NPART   2048
#define NCOMP   8192
#define NBATCH  8
#define THRESH  0.05f
#define FLTMAX  3.4028235e38f

#define SLOTS   32                        // point-slots per block
#define SEGS    32                        // partial segments (tid>>5)
#define SEGLEN  (NPART / SEGS)            // 64 partials per segment
#define PPT     8                         // completed points per thread
#define PTSBLK  (SLOTS * PPT)             // 256 completed points per block
#define BLKSPB  (NCOMP / PTSBLK)          // 32 blocks per batch
#define GRID    (NBATCH * BLKSPB)         // 256 blocks, 16 waves each
#define WAVES   16                        // per block
#define COLS    (WAVES + 1)               // smin row pitch (pad -> conflict-free)

__global__ __launch_bounds__(1024, 4) void pml_main(
    const float* __restrict__ completed,
    const float* __restrict__ partial,
    float2* __restrict__ slots_out)       // per-block (sum, cnt) -- no atomics
{
    const int tid   = threadIdx.x;
    const int slot  = tid & (SLOTS - 1);
    const int seg   = tid >> 5;              // 0..31; half-wave uniform
    const int wave  = tid >> 6;              // 0..15
    const int batch = blockIdx.x >> 5;
    const int blkb  = blockIdx.x & (BLKSPB - 1);

    __shared__ float4 sp[NPART];             // 32 KB: (x,y,z,|p|^2)
    __shared__ float  smin[PTSBLK][COLS];    // 17 KB (wave-folded segment minima)
    __shared__ float  sc2[PTSBLK];
    __shared__ float        rs[WAVES];
    __shared__ unsigned int rc[WAVES];

    // ---- stage partials into LDS, precompute |p|^2 ----
    {
        const float* pb = partial + (size_t)batch * NPART * 3;
        #pragma unroll
        for (int k = 0; k < 2; ++k) {
            int j = k * 1024 + tid;
            float x = pb[3 * j + 0];
            float y = pb[3 * j + 1];
            float z = pb[3 * j + 2];
            sp[j] = make_float4(x, y, z, fmaf(x, x, fmaf(y, y, z * z)));
        }
    }

    // ---- this thread's 8 completed points (stride-32 -> coalesced) ----
    const float* cb = completed + ((size_t)batch * NCOMP + (size_t)blkb * PTSBLK) * 3;
    float nx[PPT], ny[PPT], nz[PPT], c2[PPT];
    #pragma unroll
    for (int k = 0; k < PPT; ++k) {
        int p = slot + k * SLOTS;
        float x = cb[3 * p + 0];
        float y = cb[3 * p + 1];
        float z = cb[3 * p + 2];
        nx[k] = -2.0f * x;
        ny[k] = -2.0f * y;
        nz[k] = -2.0f * z;
        c2[k] = fmaf(x, x, fmaf(y, y, z * z));
    }

    __syncthreads();

    // ---- scan this segment's 64 partials for 8 points (IDENTICAL to R5) ----
    const float4* s = sp + seg * SEGLEN;
    float acc[PPT][4];
    #pragma unroll
    for (int k = 0; k < PPT; ++k)
        #pragma unroll
        for (int u = 0; u < 4; ++u) acc[k][u] = FLTMAX;

    for (int j = 0; j < SEGLEN; j += 4) {
        float4 p0 = s[j + 0];
        float4 p1 = s[j + 1];
        float4 p2 = s[j + 2];
        float4 p3 = s[j + 3];
        #pragma unroll
        for (int k = 0; k < PPT; ++k) {
            acc[k][0] = fminf(acc[k][0], fmaf(p0.x, nx[k], fmaf(p0.y, ny[k], fmaf(p0.z, nz[k], p0.w))));
            acc[k][1] = fminf(acc[k][1], fmaf(p1.x, nx[k], fmaf(p1.y, ny[k], fmaf(p1.z, nz[k], p1.w))));
            acc[k][2] = fminf(acc[k][2], fmaf(p2.x, nx[k], fmaf(p2.y, ny[k], fmaf(p2.z, nz[k], p2.w))));
            acc[k][3] = fminf(acc[k][3], fmaf(p3.x, nx[k], fmaf(p3.y, ny[k], fmaf(p3.z, nz[k], p3.w))));
        }
    }

    // ---- fold the wave's two segments via xor-32 shuffle, then one LDS write ----
    #pragma unroll
    for (int k = 0; k < PPT; ++k) {
        float t = fminf(fminf(acc[k][0], acc[k][1]), fminf(acc[k][2], acc[k][3]));
        t = fminf(t, __shfl_xor(t, 32, 64));       // combine seg pair (lanes share slot)
        int p = slot + k * SLOTS;
        if ((tid & 63) < 32) {
            // banks: (17*p + wave) % 32 = (17*slot + wave) % 32, distinct per slot
            smin[p][wave] = t;
            if (wave == 0) sc2[p] = c2[k];
        }
    }
    __syncthreads();

    // ---- combine 16 wave-minima per point, mask, block-reduce, store slot ----
    float        v = 0.0f;
    unsigned int c = 0u;
    if (tid < PTSBLK) {
        float t = smin[tid][0];
        #pragma unroll
        for (int g = 1; g < WAVES; ++g) t = fminf(t, smin[tid][g]);
        float m = fmaxf(sc2[tid] + t, 0.0f);
        if (m < THRESH) { v = m; c = 1u; }
        #pragma unroll
        for (int off = 32; off >= 1; off >>= 1) {
            v += __shfl_down(v, off, 64);
            c += __shfl_down(c, off, 64);
        }
        if ((tid & 63) == 0) { rs[tid >> 6] = v; rc[tid >> 6] = c; }
    }
    __syncthreads();
    if (tid == 0) {
        float        bs = 0.0f;
        unsigned int bc = 0u;
        #pragma unroll
        for (int w = 0; w < PTSBLK / 64; ++w) { bs += rs[w]; bc += rc[w]; }
        // plain stores to a private slot: no atomics, no fence, no ticket
        slots_out[blockIdx.x] = make_float2(bs, (float)bc);
    }
}

__global__ __launch_bounds__(256) void pml_fin(
    const float2* __restrict__ slots_in,
    float* __restrict__ out)
{
    const int tid = threadIdx.x;
    float2 sl = slots_in[tid];               // GRID == 256 == blockDim
    float s = sl.x, c = sl.y;
    #pragma unroll
    for (int off = 32; off >= 1; off >>= 1) {
        s += __shfl_down(s, off, 64);
        c += __shfl_down(c, off, 64);
    }
    __shared__ float ss[4], sc[4];
    if ((tid & 63) == 0) { ss[tid >> 6] = s; sc[tid >> 6] = c; }
    __syncthreads();
    if (tid == 0) {
        float s2 = ss[0] + ss[1] + ss[2] + ss[3];
        float c2 = sc[0] + sc[1] + sc[2] + sc[3];
        *out = (c2 > 0.0f) ? (s2 / (c2 + 1e-6f)) : 0.0f;   // WEIGHT = 1.0
    }
}

extern "C" void kernel_launch(void* const* d_in, const int* in_sizes, int n_in,
                              void* d_out, int out_size, void* d_ws, size_t ws_size,
                              hipStream_t stream) {
    const float* completed = (const float*)d_in[0];  // (8, 8192, 3) f32
    const float* partial   = (const float*)d_in[1];  // (8, 2048, 3) f32
    float* out = (float*)d_out;
    float2* slots = (float2*)d_ws;                   // 256 slots, all written
                                                     // every call before read:
                                                     // no memset needed

    pml_main<<<dim3(GRID), dim3(1024), 0, stream>>>(completed, partial, slots);
    pml_fin<<<dim3(1), dim3(256), 0, stream>>>(slots, out);
}